// Round 5
// baseline (873.685 us; speedup 1.0000x reference)
//
#include <hip/hip_runtime.h>
#include <stdint.h>

#define N_NODES 50000
#define N_EDGES 800000
#define IN_F 128
#define HID_F 128
#define OUT_F 128
#define CAT_F 256
#define N_STRIPS 3125  // 50000 / 16 rows per wave-strip

#define NB 64                  // partition blocks
#define NBUCK 782              // coarse buckets of 64 nodes (ceil(50000/64))
#define CHUNK_E (N_EDGES / NB) // 12500 edges per partition block
#define SLEN (NBUCK * NB)      // 50048 scan elements

typedef __bf16 bf16x8 __attribute__((ext_vector_type(8)));
typedef float f32x4 __attribute__((ext_vector_type(4)));

union BF8 {
  bf16x8 v;
  uint16_t u[8];
};

__device__ __forceinline__ uint32_t f2b(float f) {
  uint32_t u = __float_as_uint(f);
  return (u + 0x7fffu + ((u >> 16) & 1u)) >> 16;  // RNE
}

// ---- K1: fused  [blocks 0..NB) per-block bucket histogram | [NB..NB+48) weight convert
__global__ void __launch_bounds__(256) prep_hist_kernel(
    const int* __restrict__ dst, int* __restrict__ G,
    const float* __restrict__ Qw, const float* __restrict__ Ww,
    uint16_t* __restrict__ QwB, uint16_t* __restrict__ WwB) {
  if (blockIdx.x < NB) {
    __shared__ int hist[NBUCK];
    for (int k = threadIdx.x; k < NBUCK; k += 256) hist[k] = 0;
    __syncthreads();
    int base = blockIdx.x * CHUNK_E;
    for (int e = base + threadIdx.x; e < base + CHUNK_E; e += 256)
      atomicAdd(&hist[dst[e] >> 6], 1);
    __syncthreads();
    for (int k = threadIdx.x; k < NBUCK; k += 256)
      G[k * NB + blockIdx.x] = hist[k];
  } else {
    const int TOT4 = (HID_F * IN_F + OUT_F * CAT_F) / 4;  // 12288
    int i4 = (blockIdx.x - NB) * 256 + threadIdx.x;
    if (i4 >= TOT4) return;
    int base = i4 * 4;
    const float* src;
    uint16_t* dstp;
    int off;
    if (base < HID_F * IN_F) {
      src = Qw; dstp = QwB; off = base;
    } else {
      src = Ww; dstp = WwB; off = base - HID_F * IN_F;
    }
    float4 v = *(const float4*)(src + off);
    ushort4 o;
    o.x = (uint16_t)f2b(v.x); o.y = (uint16_t)f2b(v.y);
    o.z = (uint16_t)f2b(v.z); o.w = (uint16_t)f2b(v.w);
    *(ushort4*)(dstp + off) = o;
  }
}

// ---- K2: single-block exclusive scan over G[SLEN] -> offs[SLEN+1]
__global__ void __launch_bounds__(1024) scan_kernel(const int* __restrict__ G,
                                                    int* __restrict__ offs) {
  __shared__ int wsum[17];
  int t = threadIdx.x;
  int lane = t & 63;
  int wv = t >> 6;  // 16 waves
  int base = 0;
  for (int chunk = 0; chunk < 7; ++chunk) {  // 7*8192 = 57344 >= SLEN+1
    int idx0 = chunk * 8192 + t * 8;
    int c[8];
    if (idx0 + 8 <= SLEN) {
      int4 v0 = *(const int4*)(G + idx0);
      int4 v1 = *(const int4*)(G + idx0 + 4);
      c[0] = v0.x; c[1] = v0.y; c[2] = v0.z; c[3] = v0.w;
      c[4] = v1.x; c[5] = v1.y; c[6] = v1.z; c[7] = v1.w;
    } else {
#pragma unroll
      for (int j = 0; j < 8; ++j) c[j] = (idx0 + j < SLEN) ? G[idx0 + j] : 0;
    }
    int loc[8];
    int s = 0;
#pragma unroll
    for (int j = 0; j < 8; ++j) {
      loc[j] = s;
      s += c[j];
    }
    int inc = s;
#pragma unroll
    for (int d = 1; d < 64; d <<= 1) {
      int v = __shfl_up(inc, d, 64);
      if (lane >= d) inc += v;
    }
    if (lane == 63) wsum[wv] = inc;
    __syncthreads();
    if (wv == 0) {
      int x = (lane < 16) ? wsum[lane] : 0;
      int xi = x;
#pragma unroll
      for (int d = 1; d < 16; d <<= 1) {
        int v = __shfl_up(xi, d, 64);
        if (lane >= d) xi += v;
      }
      if (lane < 16) wsum[lane] = xi - x;  // exclusive wave offset
      if (lane == 15) wsum[16] = xi;       // chunk total
    }
    __syncthreads();
    int texc = base + wsum[wv] + (inc - s);
    int ctot = wsum[16];
#pragma unroll
    for (int j = 0; j < 8; ++j) {
      int i = idx0 + j;
      if (i <= SLEN) offs[i] = texc + loc[j];
    }
    base += ctot;
    __syncthreads();
  }
}

// ---- GEMM1 body: hqB = bf16(h @ Qw^T + Qb), one wave per 16-row strip
__device__ __forceinline__ void gemm1_body(int gb, const float* __restrict__ h,
                                           const uint16_t* __restrict__ QwB,
                                           const float* __restrict__ Qb,
                                           uint16_t* __restrict__ hqB) {
  int wave = (gb * 256 + (int)threadIdx.x) >> 6;
  if (wave >= N_STRIPS) return;
  int lane = threadIdx.x & 63;
  int r = lane & 15, qd = lane >> 4;
  int row0 = wave * 16;
  f32x4 acc[8];
#pragma unroll
  for (int t = 0; t < 8; ++t) acc[t] = (f32x4){0.f, 0.f, 0.f, 0.f};
  const float* aRow = h + (size_t)(row0 + r) * IN_F + qd * 8;
#pragma unroll
  for (int kt = 0; kt < 4; ++kt) {
    float4 v0 = *(const float4*)(aRow + kt * 32);
    float4 v1 = *(const float4*)(aRow + kt * 32 + 4);
    BF8 a;
    a.u[0] = (uint16_t)f2b(v0.x); a.u[1] = (uint16_t)f2b(v0.y);
    a.u[2] = (uint16_t)f2b(v0.z); a.u[3] = (uint16_t)f2b(v0.w);
    a.u[4] = (uint16_t)f2b(v1.x); a.u[5] = (uint16_t)f2b(v1.y);
    a.u[6] = (uint16_t)f2b(v1.z); a.u[7] = (uint16_t)f2b(v1.w);
#pragma unroll
    for (int t = 0; t < 8; ++t) {
      bf16x8 b = *(const bf16x8*)(QwB + (t * 16 + r) * IN_F + kt * 32 + qd * 8);
      acc[t] = __builtin_amdgcn_mfma_f32_16x16x32_bf16(a.v, b, acc[t], 0, 0, 0);
    }
  }
#pragma unroll
  for (int t = 0; t < 8; ++t) {
    float qb = Qb[t * 16 + r];
#pragma unroll
    for (int rr = 0; rr < 4; ++rr) {
      int m = row0 + qd * 4 + rr;
      hqB[(size_t)m * HID_F + t * 16 + r] = (uint16_t)f2b(acc[t][rr] + qb);
    }
  }
}

// ---- K3: fused  [blocks 0..NB) LDS-cursor scatter | [NB..) gemm1
__global__ void __launch_bounds__(256) scatter_gemm1_kernel(
    const int* __restrict__ dst, const int* __restrict__ src, const float* __restrict__ ppr,
    const int* __restrict__ offs, int2* __restrict__ rec, const float* __restrict__ h,
    const uint16_t* __restrict__ QwB, const float* __restrict__ Qb,
    uint16_t* __restrict__ hqB) {
  if (blockIdx.x < NB) {
    __shared__ int cursor[NBUCK];
    int b = blockIdx.x;
    for (int k = threadIdx.x; k < NBUCK; k += 256) cursor[k] = offs[k * NB + b];
    __syncthreads();
    int base = b * CHUNK_E;
    for (int e = base + threadIdx.x; e < base + CHUNK_E; e += 256) {
      int d = dst[e];
      int s = src[e];
      float w = ppr[e];
      int pos = atomicAdd(&cursor[d >> 6], 1);  // LDS atomic (ds_add_rtn)
      rec[pos] = make_int2(s | ((d & 63) << 20), __float_as_int(w));
    }
  } else {
    gemm1_body(blockIdx.x - NB, h, QwB, Qb, hqB);
  }
}

// ---- K4: aggregation. Block g owns nodes [g*64, g*64+64): 32KB f32 LDS accumulator.
// Waves stream the bucket's records; per record: gather hq row (dword/lane), ds_add.
__global__ void __launch_bounds__(256) aggregate_kernel(const uint16_t* __restrict__ hqB,
                                                        const int2* __restrict__ rec,
                                                        const int* __restrict__ offs,
                                                        uint16_t* __restrict__ haggB) {
  __shared__ float accum[64][128];
  __shared__ float wsum[64];
  int g = blockIdx.x;
  float* az = &accum[0][0];
  for (int i = threadIdx.x; i < 64 * 128; i += 256) az[i] = 0.f;
  if (threadIdx.x < 64) wsum[threadIdx.x] = 0.f;
  __syncthreads();

  int rbeg = offs[g * NB];
  int rend = offs[(g + 1) * NB];
  int lane = threadIdx.x & 63, wv = threadIdx.x >> 6;
  int len = rend - rbeg;
  int per = (len + 3) >> 2;
  int myBeg = rbeg + wv * per;
  int myEnd = (myBeg + per < rend) ? (myBeg + per) : rend;
  const uint32_t* hq32 = (const uint32_t*)hqB;

  for (int i0 = myBeg; i0 < myEnd; i0 += 4) {  // batch 4 records for MLP
    int2 rc[4];
#pragma unroll
    for (int q = 0; q < 4; ++q) {
      int i = i0 + q;
      rc[q] = rec[(i < myEnd) ? i : (myEnd - 1)];
    }
    uint32_t u[4];
#pragma unroll
    for (int q = 0; q < 4; ++q) u[q] = hq32[(rc[q].x & 0xFFFFF) * 64 + lane];
#pragma unroll
    for (int q = 0; q < 4; ++q) {
      float w = (i0 + q < myEnd) ? __int_as_float(rc[q].y) : 0.f;
      int local = rc[q].x >> 20;
      atomicAdd(&accum[local][lane * 2], w * __uint_as_float(u[q] << 16));
      atomicAdd(&accum[local][lane * 2 + 1], w * __uint_as_float(u[q] & 0xffff0000u));
      if (lane == 0) atomicAdd(&wsum[local], w);
    }
  }
  __syncthreads();

  // epilogue: thread t -> node local t>>2, feature quarter t&3 (32 feats = 64B out)
  int local = threadIdx.x >> 2, part = threadIdx.x & 3;
  int node = g * 64 + local;
  if (node < N_NODES) {
    float wsv = wsum[local];
    float inv = (wsv == 0.f) ? 1.f : 1.f / wsv;
    uint32_t o[16];
#pragma unroll
    for (int j = 0; j < 16; ++j) {
      float v0 = accum[local][part * 32 + j * 2] * inv;
      float v1 = accum[local][part * 32 + j * 2 + 1] * inv;
      o[j] = f2b(v0) | (f2b(v1) << 16);
    }
    uint4* d4 = (uint4*)(haggB + (size_t)node * HID_F + part * 32);
    d4[0] = make_uint4(o[0], o[1], o[2], o[3]);
    d4[1] = make_uint4(o[4], o[5], o[6], o[7]);
    d4[2] = make_uint4(o[8], o[9], o[10], o[11]);
    d4[3] = make_uint4(o[12], o[13], o[14], o[15]);
  }
}

// ---- K5: GEMM2 + epilogue: out = l2norm(leaky_relu([h|hagg] @ Ww^T + Wb))
__global__ void __launch_bounds__(256) gemm2_kernel(const float* __restrict__ h,
                                                    const uint16_t* __restrict__ haggB,
                                                    const uint16_t* __restrict__ WwB,
                                                    const float* __restrict__ Wb,
                                                    float* __restrict__ out) {
  int wave = (blockIdx.x * 256 + (int)threadIdx.x) >> 6;
  if (wave >= N_STRIPS) return;
  int lane = threadIdx.x & 63;
  int r = lane & 15, qd = lane >> 4;
  int row0 = wave * 16;
  f32x4 acc[8];
#pragma unroll
  for (int t = 0; t < 8; ++t) acc[t] = (f32x4){0.f, 0.f, 0.f, 0.f};
  const float* aRow = h + (size_t)(row0 + r) * IN_F + qd * 8;
#pragma unroll
  for (int kt = 0; kt < 8; ++kt) {
    bf16x8 av;
    if (kt < 4) {
      float4 v0 = *(const float4*)(aRow + kt * 32);
      float4 v1 = *(const float4*)(aRow + kt * 32 + 4);
      BF8 ab;
      ab.u[0] = (uint16_t)f2b(v0.x); ab.u[1] = (uint16_t)f2b(v0.y);
      ab.u[2] = (uint16_t)f2b(v0.z); ab.u[3] = (uint16_t)f2b(v0.w);
      ab.u[4] = (uint16_t)f2b(v1.x); ab.u[5] = (uint16_t)f2b(v1.y);
      ab.u[6] = (uint16_t)f2b(v1.z); ab.u[7] = (uint16_t)f2b(v1.w);
      av = ab.v;
    } else {
      av = *(const bf16x8*)(haggB + (size_t)(row0 + r) * HID_F + (kt - 4) * 32 + qd * 8);
    }
#pragma unroll
    for (int t = 0; t < 8; ++t) {
      bf16x8 b = *(const bf16x8*)(WwB + (t * 16 + r) * CAT_F + kt * 32 + qd * 8);
      acc[t] = __builtin_amdgcn_mfma_f32_16x16x32_bf16(av, b, acc[t], 0, 0, 0);
    }
  }
  float lv[8][4];
  float ss[4] = {0.f, 0.f, 0.f, 0.f};
#pragma unroll
  for (int t = 0; t < 8; ++t) {
    float wb = Wb[t * 16 + r];
#pragma unroll
    for (int rr = 0; rr < 4; ++rr) {
      float v = acc[t][rr] + wb;
      v = (v >= 0.f) ? v : 0.01f * v;
      lv[t][rr] = v;
      ss[rr] += v * v;
    }
  }
#pragma unroll
  for (int rr = 0; rr < 4; ++rr) {
    float s = ss[rr];
    s += __shfl_xor(s, 1);
    s += __shfl_xor(s, 2);
    s += __shfl_xor(s, 4);
    s += __shfl_xor(s, 8);
    float nr = sqrtf(s);
    float inv = (nr == 0.f) ? 1.f : (1.f / nr);
    int mrow = row0 + qd * 4 + rr;
    float* orow = out + (size_t)mrow * OUT_F;
#pragma unroll
    for (int t = 0; t < 8; ++t) orow[t * 16 + r] = lv[t][rr] * inv;
  }
}

extern "C" void kernel_launch(void* const* d_in, const int* in_sizes, int n_in,
                              void* d_out, int out_size, void* d_ws, size_t ws_size,
                              hipStream_t stream) {
  const float* h = (const float*)d_in[0];
  const float* ppr = (const float*)d_in[1];
  const float* Qw = (const float*)d_in[2];
  const float* Qb = (const float*)d_in[3];
  const float* Ww = (const float*)d_in[4];
  const float* Wb = (const float*)d_in[5];
  const int* src = (const int*)d_in[6];
  const int* dst = (const int*)d_in[7];
  float* out = (float*)d_out;

  char* ws = (char*)d_ws;
  size_t o = 0;
  auto alloc = [&](size_t bytes) {
    void* p = ws + o;
    o = (o + bytes + 255) & ~(size_t)255;
    return p;
  };
  uint16_t* hqB = (uint16_t*)alloc((size_t)N_NODES * HID_F * 2);    // 12.8 MB
  uint16_t* haggB = (uint16_t*)alloc((size_t)N_NODES * HID_F * 2);  // 12.8 MB
  uint16_t* QwB = (uint16_t*)alloc((size_t)HID_F * IN_F * 2);
  uint16_t* WwB = (uint16_t*)alloc((size_t)OUT_F * CAT_F * 2);
  int* G = (int*)alloc((size_t)SLEN * 4);                           // 0.2 MB
  int* offs = (int*)alloc((size_t)(SLEN + 1) * 4);                  // 0.2 MB
  int2* rec = (int2*)alloc((size_t)N_EDGES * 8);                    // 6.4 MB
  // total ~32.5 MB; no memset needed (all buffers fully written each call)

  prep_hist_kernel<<<NB + 48, 256, 0, stream>>>(dst, G, Qw, Ww, QwB, WwB);
  scan_kernel<<<1, 1024, 0, stream>>>(G, offs);
  scatter_gemm1_kernel<<<NB + 782, 256, 0, stream>>>(dst, src, ppr, offs, rec, h, QwB, Qb, hqB);
  aggregate_kernel<<<NBUCK, 256, 0, stream>>>(hqB, rec, offs, haggB);
  gemm2_kernel<<<(N_STRIPS * 64 + 255) / 256, 256, 0, stream>>>(h, haggB, WwB, Wb, out);
}

// Round 6
// 219.768 us; speedup vs baseline: 3.9755x; 3.9755x over previous
//
#include <hip/hip_runtime.h>
#include <stdint.h>

#define N_NODES 50000
#define N_EDGES 800000
#define IN_F 128
#define HID_F 128
#define OUT_F 128
#define CAT_F 256
#define N_STRIPS 3125  // 50000 / 16 rows per wave-strip

#define NB 64                  // partition blocks
#define NBUCK 782              // coarse buckets of 64 nodes (ceil(50000/64))
#define CHUNK_E (N_EDGES / NB) // 12500 edges per partition block
#define SLEN (NBUCK * NB)      // 50048 scan elements
#define BCAP 1280              // per-bucket record capacity (mean 1024, sd 32; P(>1280)~1e-15)

typedef __bf16 bf16x8 __attribute__((ext_vector_type(8)));
typedef float f32x4 __attribute__((ext_vector_type(4)));

union BF8 {
  bf16x8 v;
  uint16_t u[8];
};

__device__ __forceinline__ uint32_t f2b(float f) {
  uint32_t u = __float_as_uint(f);
  return (u + 0x7fffu + ((u >> 16) & 1u)) >> 16;  // RNE
}

// ---- K1: fused  [blocks 0..NB) per-block bucket histogram | [NB..NB+48) weight convert
__global__ void __launch_bounds__(256) prep_hist_kernel(
    const int* __restrict__ dst, int* __restrict__ G,
    const float* __restrict__ Qw, const float* __restrict__ Ww,
    uint16_t* __restrict__ QwB, uint16_t* __restrict__ WwB) {
  if (blockIdx.x < NB) {
    __shared__ int hist[NBUCK];
    for (int k = threadIdx.x; k < NBUCK; k += 256) hist[k] = 0;
    __syncthreads();
    int base = blockIdx.x * CHUNK_E;
    for (int e = base + threadIdx.x; e < base + CHUNK_E; e += 256)
      atomicAdd(&hist[dst[e] >> 6], 1);
    __syncthreads();
    for (int k = threadIdx.x; k < NBUCK; k += 256)
      G[k * NB + blockIdx.x] = hist[k];
  } else {
    const int TOT4 = (HID_F * IN_F + OUT_F * CAT_F) / 4;  // 12288
    int i4 = (blockIdx.x - NB) * 256 + threadIdx.x;
    if (i4 >= TOT4) return;
    int base = i4 * 4;
    const float* src;
    uint16_t* dstp;
    int off;
    if (base < HID_F * IN_F) {
      src = Qw; dstp = QwB; off = base;
    } else {
      src = Ww; dstp = WwB; off = base - HID_F * IN_F;
    }
    float4 v = *(const float4*)(src + off);
    ushort4 o;
    o.x = (uint16_t)f2b(v.x); o.y = (uint16_t)f2b(v.y);
    o.z = (uint16_t)f2b(v.z); o.w = (uint16_t)f2b(v.w);
    *(ushort4*)(dstp + off) = o;
  }
}

// ---- K2: single-block exclusive scan over G[SLEN] -> offs[SLEN+1]
__global__ void __launch_bounds__(1024) scan_kernel(const int* __restrict__ G,
                                                    int* __restrict__ offs) {
  __shared__ int wsum[17];
  int t = threadIdx.x;
  int lane = t & 63;
  int wv = t >> 6;  // 16 waves
  int base = 0;
  for (int chunk = 0; chunk < 7; ++chunk) {  // 7*8192 = 57344 >= SLEN+1
    int idx0 = chunk * 8192 + t * 8;
    int c[8];
    if (idx0 + 8 <= SLEN) {
      int4 v0 = *(const int4*)(G + idx0);
      int4 v1 = *(const int4*)(G + idx0 + 4);
      c[0] = v0.x; c[1] = v0.y; c[2] = v0.z; c[3] = v0.w;
      c[4] = v1.x; c[5] = v1.y; c[6] = v1.z; c[7] = v1.w;
    } else {
#pragma unroll
      for (int j = 0; j < 8; ++j) c[j] = (idx0 + j < SLEN) ? G[idx0 + j] : 0;
    }
    int loc[8];
    int s = 0;
#pragma unroll
    for (int j = 0; j < 8; ++j) {
      loc[j] = s;
      s += c[j];
    }
    int inc = s;
#pragma unroll
    for (int d = 1; d < 64; d <<= 1) {
      int v = __shfl_up(inc, d, 64);
      if (lane >= d) inc += v;
    }
    if (lane == 63) wsum[wv] = inc;
    __syncthreads();
    if (wv == 0) {
      int x = (lane < 16) ? wsum[lane] : 0;
      int xi = x;
#pragma unroll
      for (int d = 1; d < 16; d <<= 1) {
        int v = __shfl_up(xi, d, 64);
        if (lane >= d) xi += v;
      }
      if (lane < 16) wsum[lane] = xi - x;  // exclusive wave offset
      if (lane == 15) wsum[16] = xi;       // chunk total
    }
    __syncthreads();
    int texc = base + wsum[wv] + (inc - s);
    int ctot = wsum[16];
#pragma unroll
    for (int j = 0; j < 8; ++j) {
      int i = idx0 + j;
      if (i <= SLEN) offs[i] = texc + loc[j];
    }
    base += ctot;
    __syncthreads();
  }
}

// ---- GEMM1 body: hqB = bf16(h @ Qw^T + Qb), one wave per 16-row strip
__device__ __forceinline__ void gemm1_body(int gb, const float* __restrict__ h,
                                           const uint16_t* __restrict__ QwB,
                                           const float* __restrict__ Qb,
                                           uint16_t* __restrict__ hqB) {
  int wave = (gb * 256 + (int)threadIdx.x) >> 6;
  if (wave >= N_STRIPS) return;
  int lane = threadIdx.x & 63;
  int r = lane & 15, qd = lane >> 4;
  int row0 = wave * 16;
  f32x4 acc[8];
#pragma unroll
  for (int t = 0; t < 8; ++t) acc[t] = (f32x4){0.f, 0.f, 0.f, 0.f};
  const float* aRow = h + (size_t)(row0 + r) * IN_F + qd * 8;
#pragma unroll
  for (int kt = 0; kt < 4; ++kt) {
    float4 v0 = *(const float4*)(aRow + kt * 32);
    float4 v1 = *(const float4*)(aRow + kt * 32 + 4);
    BF8 a;
    a.u[0] = (uint16_t)f2b(v0.x); a.u[1] = (uint16_t)f2b(v0.y);
    a.u[2] = (uint16_t)f2b(v0.z); a.u[3] = (uint16_t)f2b(v0.w);
    a.u[4] = (uint16_t)f2b(v1.x); a.u[5] = (uint16_t)f2b(v1.y);
    a.u[6] = (uint16_t)f2b(v1.z); a.u[7] = (uint16_t)f2b(v1.w);
#pragma unroll
    for (int t = 0; t < 8; ++t) {
      bf16x8 b = *(const bf16x8*)(QwB + (t * 16 + r) * IN_F + kt * 32 + qd * 8);
      acc[t] = __builtin_amdgcn_mfma_f32_16x16x32_bf16(a.v, b, acc[t], 0, 0, 0);
    }
  }
#pragma unroll
  for (int t = 0; t < 8; ++t) {
    float qb = Qb[t * 16 + r];
#pragma unroll
    for (int rr = 0; rr < 4; ++rr) {
      int m = row0 + qd * 4 + rr;
      hqB[(size_t)m * HID_F + t * 16 + r] = (uint16_t)f2b(acc[t][rr] + qb);
    }
  }
}

// ---- K3: fused  [blocks 0..NB) LDS-cursor scatter | [NB..) gemm1
__global__ void __launch_bounds__(256) scatter_gemm1_kernel(
    const int* __restrict__ dst, const int* __restrict__ src, const float* __restrict__ ppr,
    const int* __restrict__ offs, int2* __restrict__ rec, const float* __restrict__ h,
    const uint16_t* __restrict__ QwB, const float* __restrict__ Qb,
    uint16_t* __restrict__ hqB) {
  if (blockIdx.x < NB) {
    __shared__ int cursor[NBUCK];
    int b = blockIdx.x;
    for (int k = threadIdx.x; k < NBUCK; k += 256) cursor[k] = offs[k * NB + b];
    __syncthreads();
    int base = b * CHUNK_E;
    for (int e = base + threadIdx.x; e < base + CHUNK_E; e += 256) {
      int d = dst[e];
      int s = src[e];
      float w = ppr[e];
      int pos = atomicAdd(&cursor[d >> 6], 1);  // LDS int atomic (ds_add_rtn)
      rec[pos] = make_int2(s | ((d & 63) << 20), __float_as_int(w));
    }
  } else {
    gemm1_body(blockIdx.x - NB, h, QwB, Qb, hqB);
  }
}

// ---- K4: aggregation. Block g owns bucket g (64 nodes).
// Phase 1: 64-node LDS int histogram of the bucket's records.
// Phase 2: 1-wave shfl scan -> per-node offsets + cursors.
// Phase 3: LDS-cursor scatter -> node-sorted record array in LDS.
// Phase 4: register accumulation (round-3 scheme): wave = 4 edge-subgroups x 16
//          feature-slices; dwordx4 hq gathers; shfl_xor cross-sub reduce. NO float atomics.
__global__ void __launch_bounds__(256) aggregate_kernel(const uint16_t* __restrict__ hqB,
                                                        const int2* __restrict__ rec,
                                                        const int* __restrict__ offs,
                                                        uint16_t* __restrict__ haggB) {
  __shared__ int2 srec[BCAP];
  __shared__ int hist[64];
  __shared__ int noff[65];
  __shared__ int cur[64];
  int g = blockIdx.x;
  int t = threadIdx.x;
  if (t < 64) hist[t] = 0;
  __syncthreads();

  int rbeg = offs[g * NB];
  int rend = offs[(g + 1) * NB];
  int len = rend - rbeg;

  // phase 1: histogram over local node (records coalesced from global; L2-hot on re-read)
  for (int i = t; i < len; i += 256) {
    int2 rc = rec[rbeg + i];
    atomicAdd(&hist[rc.x >> 20], 1);
  }
  __syncthreads();

  // phase 2: exclusive scan of 64 counters (wave 0)
  if (t < 64) {
    int v = hist[t];
    int inc = v;
#pragma unroll
    for (int d = 1; d < 64; d <<= 1) {
      int x = __shfl_up(inc, d, 64);
      if (t >= d) inc += x;
    }
    noff[t] = inc - v;
    cur[t] = inc - v;
    if (t == 63) noff[64] = inc;
  }
  __syncthreads();

  // phase 3: scatter into node-sorted LDS array
  for (int i = t; i < len; i += 256) {
    int2 rc = rec[rbeg + i];
    int p = atomicAdd(&cur[rc.x >> 20], 1);
    if (p < BCAP) srec[p] = rc;
  }
  __syncthreads();

  // phase 4: register aggregation, wave wv handles local nodes [wv*16, wv*16+16)
  int lane = t & 63, wv = t >> 6;
  int sub = lane >> 4, c = lane & 15;
  const uint4* hq4 = (const uint4*)hqB;
  for (int nl = wv * 16; nl < wv * 16 + 16; ++nl) {
    int node = g * 64 + nl;
    if (node >= N_NODES) continue;
    int nbeg = noff[nl], nend = noff[nl + 1];
    int m = nend - nbeg;
    float a[8];
#pragma unroll
    for (int j = 0; j < 8; ++j) a[j] = 0.f;
    float ws = 0.f;
    if (m > 0) {
      int last = nend - 1;
      for (int e0 = nbeg; e0 < nend; e0 += 16) {
        int2 rc[4];
#pragma unroll
        for (int q = 0; q < 4; ++q) {
          int i = e0 + q * 4 + sub;
          rc[q] = srec[(i < last) ? i : last];  // same addr across 16 c-lanes: broadcast
        }
        uint4 u[4];
#pragma unroll
        for (int q = 0; q < 4; ++q) u[q] = hq4[(size_t)(rc[q].x & 0xFFFFF) * 16 + c];
#pragma unroll
        for (int q = 0; q < 4; ++q) {
          float w = (e0 + q * 4 + sub <= last) ? __int_as_float(rc[q].y) : 0.f;
          ws += w;
          uint32_t x;
          x = u[q].x;
          a[0] += w * __uint_as_float(x << 16);
          a[1] += w * __uint_as_float(x & 0xffff0000u);
          x = u[q].y;
          a[2] += w * __uint_as_float(x << 16);
          a[3] += w * __uint_as_float(x & 0xffff0000u);
          x = u[q].z;
          a[4] += w * __uint_as_float(x << 16);
          a[5] += w * __uint_as_float(x & 0xffff0000u);
          x = u[q].w;
          a[6] += w * __uint_as_float(x << 16);
          a[7] += w * __uint_as_float(x & 0xffff0000u);
        }
      }
    }
#pragma unroll
    for (int j = 0; j < 8; ++j) {
      a[j] += __shfl_xor(a[j], 16);
      a[j] += __shfl_xor(a[j], 32);
    }
    ws += __shfl_xor(ws, 16);
    ws += __shfl_xor(ws, 32);
    float dnm = (ws == 0.f) ? 1.f : ws;  // safediv
    float inv = 1.f / dnm;
    if (sub == 0) {
      uint4 o;
      o.x = f2b(a[0] * inv) | (f2b(a[1] * inv) << 16);
      o.y = f2b(a[2] * inv) | (f2b(a[3] * inv) << 16);
      o.z = f2b(a[4] * inv) | (f2b(a[5] * inv) << 16);
      o.w = f2b(a[6] * inv) | (f2b(a[7] * inv) << 16);
      ((uint4*)haggB)[(size_t)node * 16 + c] = o;
    }
  }
}

// ---- K5: GEMM2 + epilogue: out = l2norm(leaky_relu([h|hagg] @ Ww^T + Wb))
__global__ void __launch_bounds__(256) gemm2_kernel(const float* __restrict__ h,
                                                    const uint16_t* __restrict__ haggB,
                                                    const uint16_t* __restrict__ WwB,
                                                    const float* __restrict__ Wb,
                                                    float* __restrict__ out) {
  int wave = (blockIdx.x * 256 + (int)threadIdx.x) >> 6;
  if (wave >= N_STRIPS) return;
  int lane = threadIdx.x & 63;
  int r = lane & 15, qd = lane >> 4;
  int row0 = wave * 16;
  f32x4 acc[8];
#pragma unroll
  for (int t = 0; t < 8; ++t) acc[t] = (f32x4){0.f, 0.f, 0.f, 0.f};
  const float* aRow = h + (size_t)(row0 + r) * IN_F + qd * 8;
#pragma unroll
  for (int kt = 0; kt < 8; ++kt) {
    bf16x8 av;
    if (kt < 4) {
      float4 v0 = *(const float4*)(aRow + kt * 32);
      float4 v1 = *(const float4*)(aRow + kt * 32 + 4);
      BF8 ab;
      ab.u[0] = (uint16_t)f2b(v0.x); ab.u[1] = (uint16_t)f2b(v0.y);
      ab.u[2] = (uint16_t)f2b(v0.z); ab.u[3] = (uint16_t)f2b(v0.w);
      ab.u[4] = (uint16_t)f2b(v1.x); ab.u[5] = (uint16_t)f2b(v1.y);
      ab.u[6] = (uint16_t)f2b(v1.z); ab.u[7] = (uint16_t)f2b(v1.w);
      av = ab.v;
    } else {
      av = *(const bf16x8*)(haggB + (size_t)(row0 + r) * HID_F + (kt - 4) * 32 + qd * 8);
    }
#pragma unroll
    for (int t = 0; t < 8; ++t) {
      bf16x8 b = *(const bf16x8*)(WwB + (t * 16 + r) * CAT_F + kt * 32 + qd * 8);
      acc[t] = __builtin_amdgcn_mfma_f32_16x16x32_bf16(av, b, acc[t], 0, 0, 0);
    }
  }
  float lv[8][4];
  float ss[4] = {0.f, 0.f, 0.f, 0.f};
#pragma unroll
  for (int t = 0; t < 8; ++t) {
    float wb = Wb[t * 16 + r];
#pragma unroll
    for (int rr = 0; rr < 4; ++rr) {
      float v = acc[t][rr] + wb;
      v = (v >= 0.f) ? v : 0.01f * v;
      lv[t][rr] = v;
      ss[rr] += v * v;
    }
  }
#pragma unroll
  for (int rr = 0; rr < 4; ++rr) {
    float s = ss[rr];
    s += __shfl_xor(s, 1);
    s += __shfl_xor(s, 2);
    s += __shfl_xor(s, 4);
    s += __shfl_xor(s, 8);
    float nr = sqrtf(s);
    float inv = (nr == 0.f) ? 1.f : (1.f / nr);
    int mrow = row0 + qd * 4 + rr;
    float* orow = out + (size_t)mrow * OUT_F;
#pragma unroll
    for (int t = 0; t < 8; ++t) orow[t * 16 + r] = lv[t][rr] * inv;
  }
}

extern "C" void kernel_launch(void* const* d_in, const int* in_sizes, int n_in,
                              void* d_out, int out_size, void* d_ws, size_t ws_size,
                              hipStream_t stream) {
  const float* h = (const float*)d_in[0];
  const float* ppr = (const float*)d_in[1];
  const float* Qw = (const float*)d_in[2];
  const float* Qb = (const float*)d_in[3];
  const float* Ww = (const float*)d_in[4];
  const float* Wb = (const float*)d_in[5];
  const int* src = (const int*)d_in[6];
  const int* dst = (const int*)d_in[7];
  float* out = (float*)d_out;

  char* ws = (char*)d_ws;
  size_t o = 0;
  auto alloc = [&](size_t bytes) {
    void* p = ws + o;
    o = (o + bytes + 255) & ~(size_t)255;
    return p;
  };
  uint16_t* hqB = (uint16_t*)alloc((size_t)N_NODES * HID_F * 2);    // 12.8 MB
  uint16_t* haggB = (uint16_t*)alloc((size_t)N_NODES * HID_F * 2);  // 12.8 MB
  uint16_t* QwB = (uint16_t*)alloc((size_t)HID_F * IN_F * 2);
  uint16_t* WwB = (uint16_t*)alloc((size_t)OUT_F * CAT_F * 2);
  int* G = (int*)alloc((size_t)SLEN * 4);                           // 0.2 MB
  int* offs = (int*)alloc((size_t)(SLEN + 1) * 4);                  // 0.2 MB
  int2* rec = (int2*)alloc((size_t)N_EDGES * 8);                    // 6.4 MB
  // total ~32.5 MB; no memset needed (all buffers fully written each call)

  prep_hist_kernel<<<NB + 48, 256, 0, stream>>>(dst, G, Qw, Ww, QwB, WwB);
  scan_kernel<<<1, 1024, 0, stream>>>(G, offs);
  scatter_gemm1_kernel<<<NB + 782, 256, 0, stream>>>(dst, src, ppr, offs, rec, h, QwB, Qb, hqB);
  aggregate_kernel<<<NBUCK, 256, 0, stream>>>(hqB, rec, offs, haggB);
  gemm2_kernel<<<(N_STRIPS * 64 + 255) / 256, 256, 0, stream>>>(h, haggB, WwB, Wb, out);
}

// Round 7
// 190.270 us; speedup vs baseline: 4.5918x; 1.1550x over previous
//
#include <hip/hip_runtime.h>
#include <stdint.h>

#define N_NODES 50000
#define N_EDGES 800000
#define IN_F 128
#define HID_F 128
#define OUT_F 128
#define CAT_F 256
#define N_STRIPS 3125  // 50000 / 16 rows per wave-strip

#define NB 256                 // partition blocks (scatter parallelism)
#define NBUCK 782              // coarse buckets of 64 nodes (ceil(50000/64))
#define CHUNK_E (N_EDGES / NB) // 3125 edges per partition block (exact)
#define BCAP 1280              // per-bucket record capacity (mean 1024, sd 32)

typedef __bf16 bf16x8 __attribute__((ext_vector_type(8)));
typedef float f32x4 __attribute__((ext_vector_type(4)));

union BF8 {
  bf16x8 v;
  uint16_t u[8];
};

__device__ __forceinline__ uint32_t f2b(float f) {
  uint32_t u = __float_as_uint(f);
  return (u + 0x7fffu + ((u >> 16) & 1u)) >> 16;  // RNE
}

// ---- K1: fused  [blocks 0..NB) per-block bucket histogram | [NB..NB+48) weight convert
__global__ void __launch_bounds__(256) prep_hist_kernel(
    const int* __restrict__ dst, int* __restrict__ G,
    const float* __restrict__ Qw, const float* __restrict__ Ww,
    uint16_t* __restrict__ QwB, uint16_t* __restrict__ WwB) {
  if (blockIdx.x < NB) {
    __shared__ int hist[NBUCK];
    for (int k = threadIdx.x; k < NBUCK; k += 256) hist[k] = 0;
    __syncthreads();
    int base = blockIdx.x * CHUNK_E;
    for (int e = base + threadIdx.x; e < base + CHUNK_E; e += 256)
      atomicAdd(&hist[dst[e] >> 6], 1);
    __syncthreads();
    for (int k = threadIdx.x; k < NBUCK; k += 256)
      G[k * NB + blockIdx.x] = hist[k];
  } else {
    const int TOT4 = (HID_F * IN_F + OUT_F * CAT_F) / 4;  // 12288
    int i4 = (blockIdx.x - NB) * 256 + threadIdx.x;
    if (i4 >= TOT4) return;
    int base = i4 * 4;
    const float* src;
    uint16_t* dstp;
    int off;
    if (base < HID_F * IN_F) {
      src = Qw; dstp = QwB; off = base;
    } else {
      src = Ww; dstp = WwB; off = base - HID_F * IN_F;
    }
    float4 v = *(const float4*)(src + off);
    ushort4 o;
    o.x = (uint16_t)f2b(v.x); o.y = (uint16_t)f2b(v.y);
    o.z = (uint16_t)f2b(v.z); o.w = (uint16_t)f2b(v.w);
    *(ushort4*)(dstp + off) = o;
  }
}

// ---- K2a: per-bucket exclusive scan over its NB=256 partition counts (one wave/bucket)
__global__ void __launch_bounds__(256) bucket_scan_kernel(const int* __restrict__ G,
                                                          int* __restrict__ Gs,
                                                          int* __restrict__ Btot) {
  int w = (blockIdx.x * 256 + (int)threadIdx.x) >> 6;  // bucket id
  if (w >= NBUCK) return;
  int lane = threadIdx.x & 63;
  int4 v = *(const int4*)(G + (size_t)w * NB + lane * 4);
  int s = v.x + v.y + v.z + v.w;
  int inc = s;
#pragma unroll
  for (int d = 1; d < 64; d <<= 1) {
    int x = __shfl_up(inc, d, 64);
    if (lane >= d) inc += x;
  }
  int exc = inc - s;
  int4 o;
  o.x = exc;
  o.y = exc + v.x;
  o.z = exc + v.x + v.y;
  o.w = exc + v.x + v.y + v.z;
  *(int4*)(Gs + (size_t)w * NB + lane * 4) = o;
  if (lane == 63) Btot[w] = inc;
}

// ---- K2b: single-wave exclusive scan of 782 bucket totals -> Bbase[783]
__global__ void base_scan_kernel(const int* __restrict__ Btot, int* __restrict__ Bbase) {
  int lane = threadIdx.x;  // 64 threads
  int c[13], loc[13];
  int s = 0;
#pragma unroll
  for (int j = 0; j < 13; ++j) {
    int i = lane * 13 + j;
    c[j] = (i < NBUCK) ? Btot[i] : 0;
    loc[j] = s;
    s += c[j];
  }
  int inc = s;
#pragma unroll
  for (int d = 1; d < 64; d <<= 1) {
    int x = __shfl_up(inc, d, 64);
    if (lane >= d) inc += x;
  }
  int exc = inc - s;
#pragma unroll
  for (int j = 0; j < 13; ++j) {
    int i = lane * 13 + j;
    if (i <= NBUCK) Bbase[i] = exc + loc[j];
  }
}

// ---- GEMM1 body: hqB = bf16(h @ Qw^T + Qb), one wave per 16-row strip
__device__ __forceinline__ void gemm1_body(int gb, const float* __restrict__ h,
                                           const uint16_t* __restrict__ QwB,
                                           const float* __restrict__ Qb,
                                           uint16_t* __restrict__ hqB) {
  int wave = (gb * 256 + (int)threadIdx.x) >> 6;
  if (wave >= N_STRIPS) return;
  int lane = threadIdx.x & 63;
  int r = lane & 15, qd = lane >> 4;
  int row0 = wave * 16;
  f32x4 acc[8];
#pragma unroll
  for (int t = 0; t < 8; ++t) acc[t] = (f32x4){0.f, 0.f, 0.f, 0.f};
  const float* aRow = h + (size_t)(row0 + r) * IN_F + qd * 8;
#pragma unroll
  for (int kt = 0; kt < 4; ++kt) {
    float4 v0 = *(const float4*)(aRow + kt * 32);
    float4 v1 = *(const float4*)(aRow + kt * 32 + 4);
    BF8 a;
    a.u[0] = (uint16_t)f2b(v0.x); a.u[1] = (uint16_t)f2b(v0.y);
    a.u[2] = (uint16_t)f2b(v0.z); a.u[3] = (uint16_t)f2b(v0.w);
    a.u[4] = (uint16_t)f2b(v1.x); a.u[5] = (uint16_t)f2b(v1.y);
    a.u[6] = (uint16_t)f2b(v1.z); a.u[7] = (uint16_t)f2b(v1.w);
#pragma unroll
    for (int t = 0; t < 8; ++t) {
      bf16x8 b = *(const bf16x8*)(QwB + (t * 16 + r) * IN_F + kt * 32 + qd * 8);
      acc[t] = __builtin_amdgcn_mfma_f32_16x16x32_bf16(a.v, b, acc[t], 0, 0, 0);
    }
  }
#pragma unroll
  for (int t = 0; t < 8; ++t) {
    float qb = Qb[t * 16 + r];
#pragma unroll
    for (int rr = 0; rr < 4; ++rr) {
      int m = row0 + qd * 4 + rr;
      hqB[(size_t)m * HID_F + t * 16 + r] = (uint16_t)f2b(acc[t][rr] + qb);
    }
  }
}

// ---- K3: fused  [blocks 0..NB) LDS-cursor scatter | [NB..) gemm1
__global__ void __launch_bounds__(256) scatter_gemm1_kernel(
    const int* __restrict__ dst, const int* __restrict__ src, const float* __restrict__ ppr,
    const int* __restrict__ Gs, const int* __restrict__ Bbase, int2* __restrict__ rec,
    const float* __restrict__ h, const uint16_t* __restrict__ QwB,
    const float* __restrict__ Qb, uint16_t* __restrict__ hqB) {
  if (blockIdx.x < NB) {
    __shared__ int cursor[NBUCK];
    int b = blockIdx.x;
    for (int k = threadIdx.x; k < NBUCK; k += 256)
      cursor[k] = Bbase[k] + Gs[(size_t)k * NB + b];
    __syncthreads();
    int base = b * CHUNK_E;
    for (int e = base + threadIdx.x; e < base + CHUNK_E; e += 256) {
      int d = dst[e];
      int s = src[e];
      float w = ppr[e];
      int pos = atomicAdd(&cursor[d >> 6], 1);  // LDS int atomic
      rec[pos] = make_int2(s | ((d & 63) << 20), __float_as_int(w));
    }
  } else {
    gemm1_body(blockIdx.x - NB, h, QwB, Qb, hqB);
  }
}

// ---- K4: fused aggregation + GEMM2. Block g owns bucket g (64 nodes).
// Phases 1-3: LDS reorder of the bucket's records into node-sorted srec.
// Phase 4: register aggregation (wave wv -> local nodes [16wv,16wv+16)); hagg -> padded LDS.
// Phase 5: gemm2 strip (rows g*64+wv*16 .. +16): A = [f32 h | LDS hagg], epilogue+store.
__global__ void __launch_bounds__(256) agg_gemm2_kernel(
    const uint16_t* __restrict__ hqB, const int2* __restrict__ rec,
    const int* __restrict__ Bbase, const float* __restrict__ h,
    const uint16_t* __restrict__ WwB, const float* __restrict__ Wb,
    float* __restrict__ out) {
  __shared__ int2 srec[BCAP];       // 10.0 KB
  __shared__ uint4 hagg[64][17];    // 17.0 KB (pad 16->17 breaks stride-256B bank conflict)
  __shared__ int hist[64];
  __shared__ int noff[65];
  __shared__ int cur[64];
  int g = blockIdx.x;
  int t = threadIdx.x;
  if (t < 64) hist[t] = 0;
  __syncthreads();

  int rbeg = Bbase[g];
  int rend = Bbase[g + 1];
  int len = rend - rbeg;

  // phase 1: 64-node histogram
  for (int i = t; i < len; i += 256) {
    int2 rc = rec[rbeg + i];
    atomicAdd(&hist[rc.x >> 20], 1);
  }
  __syncthreads();

  // phase 2: exclusive scan of 64 counters (wave 0)
  if (t < 64) {
    int v = hist[t];
    int inc = v;
#pragma unroll
    for (int d = 1; d < 64; d <<= 1) {
      int x = __shfl_up(inc, d, 64);
      if (t >= d) inc += x;
    }
    noff[t] = inc - v;
    cur[t] = inc - v;
    if (t == 63) noff[64] = inc;
  }
  __syncthreads();

  // phase 3: scatter into node-sorted LDS array
  for (int i = t; i < len; i += 256) {
    int2 rc = rec[rbeg + i];
    int p = atomicAdd(&cur[rc.x >> 20], 1);
    if (p < BCAP) srec[p] = rc;
  }
  __syncthreads();

  // phase 4: register aggregation. wave = 4 edge-subgroups x 16 feature-slices.
  int lane = t & 63, wv = t >> 6;
  int sub = lane >> 4, c = lane & 15;
  const uint4* hq4 = (const uint4*)hqB;
  for (int nl = wv * 16; nl < wv * 16 + 16; ++nl) {
    int node = g * 64 + nl;
    if (node >= N_NODES) continue;
    int nbeg = noff[nl], nend = noff[nl + 1];
    int m = nend - nbeg;
    float a[8];
#pragma unroll
    for (int j = 0; j < 8; ++j) a[j] = 0.f;
    float ws = 0.f;
    if (m > 0) {
      int last = nend - 1;
      for (int e0 = nbeg; e0 < nend; e0 += 16) {
        int2 rc[4];
#pragma unroll
        for (int q = 0; q < 4; ++q) {
          int i = e0 + q * 4 + sub;
          rc[q] = srec[(i < last) ? i : last];  // same addr across 16 c-lanes: broadcast
        }
        uint4 u[4];
#pragma unroll
        for (int q = 0; q < 4; ++q) u[q] = hq4[(size_t)(rc[q].x & 0xFFFFF) * 16 + c];
#pragma unroll
        for (int q = 0; q < 4; ++q) {
          float w = (e0 + q * 4 + sub <= last) ? __int_as_float(rc[q].y) : 0.f;
          ws += w;
          uint32_t x;
          x = u[q].x;
          a[0] += w * __uint_as_float(x << 16);
          a[1] += w * __uint_as_float(x & 0xffff0000u);
          x = u[q].y;
          a[2] += w * __uint_as_float(x << 16);
          a[3] += w * __uint_as_float(x & 0xffff0000u);
          x = u[q].z;
          a[4] += w * __uint_as_float(x << 16);
          a[5] += w * __uint_as_float(x & 0xffff0000u);
          x = u[q].w;
          a[6] += w * __uint_as_float(x << 16);
          a[7] += w * __uint_as_float(x & 0xffff0000u);
        }
      }
    }
#pragma unroll
    for (int j = 0; j < 8; ++j) {
      a[j] += __shfl_xor(a[j], 16);
      a[j] += __shfl_xor(a[j], 32);
    }
    ws += __shfl_xor(ws, 16);
    ws += __shfl_xor(ws, 32);
    float dnm = (ws == 0.f) ? 1.f : ws;  // safediv
    float inv = 1.f / dnm;
    if (sub == 0) {
      uint4 o;
      o.x = f2b(a[0] * inv) | (f2b(a[1] * inv) << 16);
      o.y = f2b(a[2] * inv) | (f2b(a[3] * inv) << 16);
      o.z = f2b(a[4] * inv) | (f2b(a[5] * inv) << 16);
      o.w = f2b(a[6] * inv) | (f2b(a[7] * inv) << 16);
      hagg[nl][c] = o;
    }
  }
  __syncthreads();

  // phase 5: gemm2 on this wave's own strip
  int row0 = g * 64 + wv * 16;
  if (row0 >= N_NODES) return;
  int r = lane & 15, qd = lane >> 4;
  f32x4 acc[8];
#pragma unroll
  for (int tt = 0; tt < 8; ++tt) acc[tt] = (f32x4){0.f, 0.f, 0.f, 0.f};
  const float* aRow = h + (size_t)(row0 + r) * IN_F + qd * 8;
#pragma unroll
  for (int kt = 0; kt < 8; ++kt) {
    bf16x8 av;
    if (kt < 4) {
      float4 v0 = *(const float4*)(aRow + kt * 32);
      float4 v1 = *(const float4*)(aRow + kt * 32 + 4);
      BF8 ab;
      ab.u[0] = (uint16_t)f2b(v0.x); ab.u[1] = (uint16_t)f2b(v0.y);
      ab.u[2] = (uint16_t)f2b(v0.z); ab.u[3] = (uint16_t)f2b(v0.w);
      ab.u[4] = (uint16_t)f2b(v1.x); ab.u[5] = (uint16_t)f2b(v1.y);
      ab.u[6] = (uint16_t)f2b(v1.z); ab.u[7] = (uint16_t)f2b(v1.w);
      av = ab.v;
    } else {
      av = *(const bf16x8*)&hagg[wv * 16 + r][(kt - 4) * 4 + qd];
    }
#pragma unroll
    for (int tt = 0; tt < 8; ++tt) {
      bf16x8 b = *(const bf16x8*)(WwB + (tt * 16 + r) * CAT_F + kt * 32 + qd * 8);
      acc[tt] = __builtin_amdgcn_mfma_f32_16x16x32_bf16(av, b, acc[tt], 0, 0, 0);
    }
  }
  float lv[8][4];
  float ss[4] = {0.f, 0.f, 0.f, 0.f};
#pragma unroll
  for (int tt = 0; tt < 8; ++tt) {
    float wb = Wb[tt * 16 + r];
#pragma unroll
    for (int rr = 0; rr < 4; ++rr) {
      float v = acc[tt][rr] + wb;
      v = (v >= 0.f) ? v : 0.01f * v;
      lv[tt][rr] = v;
      ss[rr] += v * v;
    }
  }
#pragma unroll
  for (int rr = 0; rr < 4; ++rr) {
    float s = ss[rr];
    s += __shfl_xor(s, 1);
    s += __shfl_xor(s, 2);
    s += __shfl_xor(s, 4);
    s += __shfl_xor(s, 8);
    float nr = sqrtf(s);
    float inv = (nr == 0.f) ? 1.f : (1.f / nr);
    int mrow = row0 + qd * 4 + rr;
    float* orow = out + (size_t)mrow * OUT_F;
#pragma unroll
    for (int tt = 0; tt < 8; ++tt) orow[tt * 16 + r] = lv[tt][rr] * inv;
  }
}

extern "C" void kernel_launch(void* const* d_in, const int* in_sizes, int n_in,
                              void* d_out, int out_size, void* d_ws, size_t ws_size,
                              hipStream_t stream) {
  const float* h = (const float*)d_in[0];
  const float* ppr = (const float*)d_in[1];
  const float* Qw = (const float*)d_in[2];
  const float* Qb = (const float*)d_in[3];
  const float* Ww = (const float*)d_in[4];
  const float* Wb = (const float*)d_in[5];
  const int* src = (const int*)d_in[6];
  const int* dst = (const int*)d_in[7];
  float* out = (float*)d_out;

  char* ws = (char*)d_ws;
  size_t o = 0;
  auto alloc = [&](size_t bytes) {
    void* p = ws + o;
    o = (o + bytes + 255) & ~(size_t)255;
    return p;
  };
  uint16_t* hqB = (uint16_t*)alloc((size_t)N_NODES * HID_F * 2);  // 12.8 MB
  uint16_t* QwB = (uint16_t*)alloc((size_t)HID_F * IN_F * 2);
  uint16_t* WwB = (uint16_t*)alloc((size_t)OUT_F * CAT_F * 2);
  int* G = (int*)alloc((size_t)NBUCK * NB * 4);    // 0.8 MB
  int* Gs = (int*)alloc((size_t)NBUCK * NB * 4);   // 0.8 MB
  int* Btot = (int*)alloc((size_t)NBUCK * 4);
  int* Bbase = (int*)alloc((size_t)(NBUCK + 1) * 4);
  int2* rec = (int2*)alloc((size_t)N_EDGES * 8);   // 6.4 MB
  // total ~21 MB; no memset needed (all buffers fully written each call)

  prep_hist_kernel<<<NB + 48, 256, 0, stream>>>(dst, G, Qw, Ww, QwB, WwB);
  bucket_scan_kernel<<<(NBUCK + 3) / 4, 256, 0, stream>>>(G, Gs, Btot);
  base_scan_kernel<<<1, 64, 0, stream>>>(Btot, Bbase);
  scatter_gemm1_kernel<<<NB + 782, 256, 0, stream>>>(dst, src, ppr, Gs, Bbase, rec, h, QwB,
                                                     Qb, hqB);
  agg_gemm2_kernel<<<NBUCK, 256, 0, stream>>>(hqB, rec, Bbase, h, WwB, Wb, out);
}

// Round 8
// 179.764 us; speedup vs baseline: 4.8602x; 1.0584x over previous
//
#include <hip/hip_runtime.h>
#include <stdint.h>

#define N_NODES 50000
#define N_EDGES 800000
#define IN_F 128
#define HID_F 128
#define OUT_F 128
#define CAT_F 256
#define N_STRIPS 3125  // 50000 / 16 rows per wave-strip

#define NB 256            // edge partition blocks
#define CHUNK 3136        // edges per partition (int4-aligned; 256*3136 >= 800000)
#define NBUCK 1563        // 32-node buckets (ceil(50000/32))
#define BCAP 640          // per-bucket record capacity (mean 512, +5.7 sigma)

typedef __bf16 bf16x8 __attribute__((ext_vector_type(8)));
typedef float f32x4 __attribute__((ext_vector_type(4)));

__device__ __forceinline__ uint32_t f2b(float f) {
  uint32_t u = __float_as_uint(f);
  return (u + 0x7fffu + ((u >> 16) & 1u)) >> 16;  // RNE
}

// ---- K1: fused  [0,NB): per-partition bucket histogram | [NB,..): h/Qw/Ww -> bf16
__global__ void __launch_bounds__(256) prep_hist_kernel(
    const int* __restrict__ dst, int* __restrict__ G, const float* __restrict__ h,
    const float* __restrict__ Qw, const float* __restrict__ Ww, uint16_t* __restrict__ hB,
    uint16_t* __restrict__ QwB, uint16_t* __restrict__ WwB) {
  if (blockIdx.x < NB) {
    __shared__ int hist[NBUCK];
    for (int k = threadIdx.x; k < NBUCK; k += 256) hist[k] = 0;
    __syncthreads();
    int b = blockIdx.x;
    int base = b * CHUNK;
    int end = (base + CHUNK < N_EDGES) ? (base + CHUNK) : N_EDGES;
    for (int i4 = base / 4 + threadIdx.x; i4 * 4 < end; i4 += 256) {
      int4 d4 = ((const int4*)dst)[i4];  // CHUNK,N_EDGES divisible by 4
      atomicAdd(&hist[d4.x >> 5], 1);
      atomicAdd(&hist[d4.y >> 5], 1);
      atomicAdd(&hist[d4.z >> 5], 1);
      atomicAdd(&hist[d4.w >> 5], 1);
    }
    __syncthreads();
    for (int k = threadIdx.x; k < NBUCK; k += 256) G[k * NB + b] = hist[k];
  } else {
    const int TOT4 = (N_NODES * IN_F + HID_F * IN_F + OUT_F * CAT_F) / 4;  // 1612288
    int i4 = (blockIdx.x - NB) * 256 + threadIdx.x;
    if (i4 >= TOT4) return;
    int base = i4 * 4;
    const float* src;
    uint16_t* dstp;
    int off;
    if (base < N_NODES * IN_F) {
      src = h; dstp = hB; off = base;
    } else if (base < N_NODES * IN_F + HID_F * IN_F) {
      src = Qw; dstp = QwB; off = base - N_NODES * IN_F;
    } else {
      src = Ww; dstp = WwB; off = base - N_NODES * IN_F - HID_F * IN_F;
    }
    float4 v = *(const float4*)(src + off);
    ushort4 o;
    o.x = (uint16_t)f2b(v.x); o.y = (uint16_t)f2b(v.y);
    o.z = (uint16_t)f2b(v.z); o.w = (uint16_t)f2b(v.w);
    *(ushort4*)(dstp + off) = o;
  }
}

// ---- K2a: per-bucket exclusive scan over its NB=256 partition counts (one wave/bucket)
__global__ void __launch_bounds__(256) bucket_scan_kernel(const int* __restrict__ G,
                                                          int* __restrict__ Gs,
                                                          int* __restrict__ Btot) {
  int w = (blockIdx.x * 256 + (int)threadIdx.x) >> 6;  // bucket id
  if (w >= NBUCK) return;
  int lane = threadIdx.x & 63;
  int4 v = *(const int4*)(G + (size_t)w * NB + lane * 4);
  int s = v.x + v.y + v.z + v.w;
  int inc = s;
#pragma unroll
  for (int d = 1; d < 64; d <<= 1) {
    int x = __shfl_up(inc, d, 64);
    if (lane >= d) inc += x;
  }
  int exc = inc - s;
  int4 o;
  o.x = exc;
  o.y = exc + v.x;
  o.z = exc + v.x + v.y;
  o.w = exc + v.x + v.y + v.z;
  *(int4*)(Gs + (size_t)w * NB + lane * 4) = o;
  if (lane == 63) Btot[w] = inc;
}

// ---- K2b: single-wave exclusive scan of NBUCK bucket totals -> Bbase[NBUCK+1]
__global__ void base_scan_kernel(const int* __restrict__ Btot, int* __restrict__ Bbase) {
  int lane = threadIdx.x;  // 64 threads, 25 elems each (1600 >= 1564)
  int c[25], loc[25];
  int s = 0;
#pragma unroll
  for (int j = 0; j < 25; ++j) {
    int i = lane * 25 + j;
    c[j] = (i < NBUCK) ? Btot[i] : 0;
    loc[j] = s;
    s += c[j];
  }
  int inc = s;
#pragma unroll
  for (int d = 1; d < 64; d <<= 1) {
    int x = __shfl_up(inc, d, 64);
    if (lane >= d) inc += x;
  }
  int exc = inc - s;
#pragma unroll
  for (int j = 0; j < 25; ++j) {
    int i = lane * 25 + j;
    if (i <= NBUCK) Bbase[i] = exc + loc[j];
  }
}

// ---- GEMM1 body: hq = bf16(hB @ Qw^T + Qb), one wave per 16-row strip
__device__ __forceinline__ void gemm1_body(int gb, const uint16_t* __restrict__ hB,
                                           const uint16_t* __restrict__ QwB,
                                           const float* __restrict__ Qb,
                                           uint16_t* __restrict__ hqB) {
  int wave = (gb * 256 + (int)threadIdx.x) >> 6;
  if (wave >= N_STRIPS) return;
  int lane = threadIdx.x & 63;
  int r = lane & 15, qd = lane >> 4;
  int row0 = wave * 16;
  f32x4 acc[8];
#pragma unroll
  for (int t = 0; t < 8; ++t) acc[t] = (f32x4){0.f, 0.f, 0.f, 0.f};
  const uint16_t* aRow = hB + (size_t)(row0 + r) * IN_F + qd * 8;
#pragma unroll
  for (int kt = 0; kt < 4; ++kt) {
    bf16x8 a = *(const bf16x8*)(aRow + kt * 32);
#pragma unroll
    for (int t = 0; t < 8; ++t) {
      bf16x8 b = *(const bf16x8*)(QwB + (t * 16 + r) * IN_F + kt * 32 + qd * 8);
      acc[t] = __builtin_amdgcn_mfma_f32_16x16x32_bf16(a, b, acc[t], 0, 0, 0);
    }
  }
#pragma unroll
  for (int t = 0; t < 8; ++t) {
    float qb = Qb[t * 16 + r];
#pragma unroll
    for (int rr = 0; rr < 4; ++rr) {
      int m = row0 + qd * 4 + rr;
      hqB[(size_t)m * HID_F + t * 16 + r] = (uint16_t)f2b(acc[t][rr] + qb);
    }
  }
}

// ---- K3: fused  [0,NB): LDS-cursor scatter (int4 edge loads) | [NB,..): gemm1
__global__ void __launch_bounds__(256) scatter_gemm1_kernel(
    const int* __restrict__ dst, const int* __restrict__ src, const float* __restrict__ ppr,
    const int* __restrict__ Gs, const int* __restrict__ Bbase, int2* __restrict__ rec,
    const uint16_t* __restrict__ hB, const uint16_t* __restrict__ QwB,
    const float* __restrict__ Qb, uint16_t* __restrict__ hqB) {
  if (blockIdx.x < NB) {
    __shared__ int cursor[NBUCK];
    int b = blockIdx.x;
    for (int k = threadIdx.x; k < NBUCK; k += 256)
      cursor[k] = Bbase[k] + Gs[(size_t)k * NB + b];
    __syncthreads();
    int base = b * CHUNK;
    int end = (base + CHUNK < N_EDGES) ? (base + CHUNK) : N_EDGES;
    for (int i4 = base / 4 + threadIdx.x; i4 * 4 < end; i4 += 256) {
      int4 d4 = ((const int4*)dst)[i4];
      int4 s4 = ((const int4*)src)[i4];
      float4 w4 = ((const float4*)ppr)[i4];
      int p;
      p = atomicAdd(&cursor[d4.x >> 5], 1);
      rec[p] = make_int2(s4.x | ((d4.x & 31) << 20), __float_as_int(w4.x));
      p = atomicAdd(&cursor[d4.y >> 5], 1);
      rec[p] = make_int2(s4.y | ((d4.y & 31) << 20), __float_as_int(w4.y));
      p = atomicAdd(&cursor[d4.z >> 5], 1);
      rec[p] = make_int2(s4.z | ((d4.z & 31) << 20), __float_as_int(w4.z));
      p = atomicAdd(&cursor[d4.w >> 5], 1);
      rec[p] = make_int2(s4.w | ((d4.w & 31) << 20), __float_as_int(w4.w));
    }
  } else {
    gemm1_body(blockIdx.x - NB, hB, QwB, Qb, hqB);
  }
}

// ---- K4: fused aggregation + GEMM2. Block g (128 thr, 2 waves) owns 32 nodes.
// P1: load bucket records into registers + LDS histogram. P2: 32-counter scan.
// P3: register->LDS node-sorted scatter. P4: sub-as-node register aggregation
// (each 16-lane sub owns one node; 4-deep edge batches; no cross-lane reduce).
// P5: gemm2 strip per wave from [hB | LDS hagg].
__global__ void __launch_bounds__(128) agg_gemm2_kernel(
    const uint16_t* __restrict__ hqB, const int2* __restrict__ rec,
    const int* __restrict__ Bbase, const uint16_t* __restrict__ hB,
    const uint16_t* __restrict__ WwB, const float* __restrict__ Wb,
    float* __restrict__ out) {
  __shared__ int2 srec[BCAP];     // 5.1 KB
  __shared__ uint4 hagg[32][17];  // 8.7 KB (pad 16->17 breaks stride conflicts)
  __shared__ int hist[32];
  __shared__ int noff[33];
  __shared__ int cur[32];
  int g = blockIdx.x;
  int t = threadIdx.x;
  if (t < 32) hist[t] = 0;
  __syncthreads();

  int rbeg = Bbase[g];
  int len = Bbase[g + 1] - rbeg;
  len = (len < BCAP) ? len : BCAP;

  // P1: load to registers + histogram
  int2 rc[5];
#pragma unroll
  for (int k = 0; k < 5; ++k) {
    int i = t + k * 128;
    if (i < len) {
      rc[k] = rec[rbeg + i];
      atomicAdd(&hist[rc[k].x >> 20], 1);
    }
  }
  __syncthreads();

  // P2: exclusive scan of 32 counters (lanes 0..31 of wave 0)
  if (t < 32) {
    int v = hist[t];
    int inc = v;
#pragma unroll
    for (int d = 1; d < 32; d <<= 1) {
      int x = __shfl_up(inc, d, 64);
      if (t >= d) inc += x;
    }
    noff[t] = inc - v;
    cur[t] = inc - v;
    if (t == 31) noff[32] = inc;
  }
  __syncthreads();

  // P3: scatter registers -> node-sorted LDS
#pragma unroll
  for (int k = 0; k < 5; ++k) {
    int i = t + k * 128;
    if (i < len) {
      int p = atomicAdd(&cur[rc[k].x >> 20], 1);
      srec[p] = rc[k];
    }
  }
  __syncthreads();

  // P4: sub-as-node aggregation
  int lane = t & 63, wv = t >> 6;
  int sub = lane >> 4, c = lane & 15;
  const uint4* hq4 = (const uint4*)hqB;
#pragma unroll
  for (int g4 = 0; g4 < 4; ++g4) {
    int nl = wv * 16 + g4 * 4 + sub;
    int node = g * 32 + nl;
    if (node < N_NODES) {
      int nbeg = noff[nl], nend = noff[nl + 1];
      float a[8];
#pragma unroll
      for (int j = 0; j < 8; ++j) a[j] = 0.f;
      float ws = 0.f;
      for (int e0 = nbeg; e0 < nend; e0 += 4) {
        int last = nend - 1;
        int2 rr[4];
#pragma unroll
        for (int j = 0; j < 4; ++j) {
          int i = e0 + j;
          rr[j] = srec[(i < last) ? i : last];  // same addr across 16 c-lanes: broadcast
        }
        uint4 u[4];
#pragma unroll
        for (int j = 0; j < 4; ++j) u[j] = hq4[(size_t)(rr[j].x & 0xFFFFF) * 16 + c];
#pragma unroll
        for (int j = 0; j < 4; ++j) {
          float w = (e0 + j < nend) ? __int_as_float(rr[j].y) : 0.f;
          ws += w;
          uint32_t x;
          x = u[j].x;
          a[0] += w * __uint_as_float(x << 16);
          a[1] += w * __uint_as_float(x & 0xffff0000u);
          x = u[j].y;
          a[2] += w * __uint_as_float(x << 16);
          a[3] += w * __uint_as_float(x & 0xffff0000u);
          x = u[j].z;
          a[4] += w * __uint_as_float(x << 16);
          a[5] += w * __uint_as_float(x & 0xffff0000u);
          x = u[j].w;
          a[6] += w * __uint_as_float(x << 16);
          a[7] += w * __uint_as_float(x & 0xffff0000u);
        }
      }
      float dnm = (ws == 0.f) ? 1.f : ws;  // safediv
      float inv = 1.f / dnm;
      uint4 o;
      o.x = f2b(a[0] * inv) | (f2b(a[1] * inv) << 16);
      o.y = f2b(a[2] * inv) | (f2b(a[3] * inv) << 16);
      o.z = f2b(a[4] * inv) | (f2b(a[5] * inv) << 16);
      o.w = f2b(a[6] * inv) | (f2b(a[7] * inv) << 16);
      hagg[nl][c] = o;
    }
  }
  __syncthreads();

  // P5: gemm2 on this wave's strip
  int row0 = g * 32 + wv * 16;
  if (row0 >= N_NODES) return;
  int r = lane & 15, qd = lane >> 4;
  f32x4 acc[8];
#pragma unroll
  for (int tt = 0; tt < 8; ++tt) acc[tt] = (f32x4){0.f, 0.f, 0.f, 0.f};
  const uint16_t* aRow = hB + (size_t)(row0 + r) * IN_F + qd * 8;
#pragma unroll
  for (int kt = 0; kt < 8; ++kt) {
    bf16x8 av;
    if (kt < 4) {
      av = *(const bf16x8*)(aRow + kt * 32);
    } else {
      av = *(const bf16x8*)&hagg[wv * 16 + r][(kt - 4) * 4 + qd];
    }
#pragma unroll
    for (int tt = 0; tt < 8; ++tt) {
      bf16x8 b = *(const bf16x8*)(WwB + (tt * 16 + r) * CAT_F + kt * 32 + qd * 8);
      acc[tt] = __builtin_amdgcn_mfma_f32_16x16x32_bf16(av, b, acc[tt], 0, 0, 0);
    }
  }
  float lv[8][4];
  float ss[4] = {0.f, 0.f, 0.f, 0.f};
#pragma unroll
  for (int tt = 0; tt < 8; ++tt) {
    float wb = Wb[tt * 16 + r];
#pragma unroll
    for (int rr2 = 0; rr2 < 4; ++rr2) {
      float v = acc[tt][rr2] + wb;
      v = (v >= 0.f) ? v : 0.01f * v;
      lv[tt][rr2] = v;
      ss[rr2] += v * v;
    }
  }
#pragma unroll
  for (int rr2 = 0; rr2 < 4; ++rr2) {
    float s = ss[rr2];
    s += __shfl_xor(s, 1);
    s += __shfl_xor(s, 2);
    s += __shfl_xor(s, 4);
    s += __shfl_xor(s, 8);
    float nr = sqrtf(s);
    float inv = (nr == 0.f) ? 1.f : (1.f / nr);
    int mrow = row0 + qd * 4 + rr2;
    float* orow = out + (size_t)mrow * OUT_F;
#pragma unroll
    for (int tt = 0; tt < 8; ++tt) orow[tt * 16 + r] = lv[tt][rr2] * inv;
  }
}

extern "C" void kernel_launch(void* const* d_in, const int* in_sizes, int n_in,
                              void* d_out, int out_size, void* d_ws, size_t ws_size,
                              hipStream_t stream) {
  const float* h = (const float*)d_in[0];
  const float* ppr = (const float*)d_in[1];
  const float* Qw = (const float*)d_in[2];
  const float* Qb = (const float*)d_in[3];
  const float* Ww = (const float*)d_in[4];
  const float* Wb = (const float*)d_in[5];
  const int* src = (const int*)d_in[6];
  const int* dst = (const int*)d_in[7];
  float* out = (float*)d_out;

  char* ws = (char*)d_ws;
  size_t o = 0;
  auto alloc = [&](size_t bytes) {
    void* p = ws + o;
    o = (o + bytes + 255) & ~(size_t)255;
    return p;
  };
  uint16_t* hB = (uint16_t*)alloc((size_t)N_NODES * IN_F * 2);   // 12.8 MB
  uint16_t* hqB = (uint16_t*)alloc((size_t)N_NODES * HID_F * 2); // 12.8 MB
  uint16_t* QwB = (uint16_t*)alloc((size_t)HID_F * IN_F * 2);
  uint16_t* WwB = (uint16_t*)alloc((size_t)OUT_F * CAT_F * 2);
  int* G = (int*)alloc((size_t)NBUCK * NB * 4);   // 1.6 MB
  int* Gs = (int*)alloc((size_t)NBUCK * NB * 4);  // 1.6 MB
  int* Btot = (int*)alloc((size_t)NBUCK * 4);
  int* Bbase = (int*)alloc((size_t)(NBUCK + 1) * 4);
  int2* rec = (int2*)alloc((size_t)N_EDGES * 8);  // 6.4 MB
  // total ~35.5 MB; no memset needed (all buffers fully written each call)

  const int CONV_BLOCKS = ((N_NODES * IN_F + HID_F * IN_F + OUT_F * CAT_F) / 4 + 255) / 256;
  prep_hist_kernel<<<NB + CONV_BLOCKS, 256, 0, stream>>>(dst, G, h, Qw, Ww, hB, QwB, WwB);
  bucket_scan_kernel<<<(NBUCK + 3) / 4, 256, 0, stream>>>(G, Gs, Btot);
  base_scan_kernel<<<1, 64, 0, stream>>>(Btot, Bbase);
  scatter_gemm1_kernel<<<NB + 782, 256, 0, stream>>>(dst, src, ppr, Gs, Bbase, rec, hB, QwB,
                                                     Qb, hqB);
  agg_gemm2_kernel<<<NBUCK, 128, 0, stream>>>(hqB, rec, Bbase, hB, WwB, Wb, out);
}